// Round 7
// baseline (216.143 us; speedup 1.0000x reference)
//
#include <hip/hip_runtime.h>

#define EMB 512
#define HEADS 8
#define HD 64
#define NSEQ 4096
#define BATCH 2
#define WINDOW 128

typedef unsigned short u16;
typedef __attribute__((ext_vector_type(8))) short bf16x8;
typedef __attribute__((ext_vector_type(4))) float f32x4;

__device__ __forceinline__ float bf2f(u16 u) {
    union { unsigned int i; float f; } x;
    x.i = ((unsigned int)u) << 16;
    return x.f;
}

__device__ __forceinline__ u16 f2bf(float f) {
    union { float f; unsigned int i; } x;
    x.f = f;
    unsigned int i = x.i;
    unsigned int lsb = (i >> 16) & 1u;
    i += 0x7fffu + lsb;   // round-to-nearest-even
    return (u16)(i >> 16);
}

struct raw8 { uint4 lo, hi; };   // bf16: lo only; fp32: lo+hi

__device__ __forceinline__ raw8 loadraw8(const void* base, size_t off, int isbf) {
    raw8 r;
    if (isbf) {
        r.lo = *(const uint4*)((const u16*)base + off);
    } else {
        const float* f = (const float*)base + off;
        r.lo = *(const uint4*)f;
        r.hi = *(const uint4*)(f + 4);
    }
    return r;
}

__device__ __forceinline__ uint4 cvt8(const raw8& r, int isbf) {
    if (isbf) return r.lo;
    const float* a = (const float*)&r.lo;
    const float* b = (const float*)&r.hi;
    uint4 o;
    o.x = (unsigned)f2bf(a[0]) | ((unsigned)f2bf(a[1]) << 16);
    o.y = (unsigned)f2bf(a[2]) | ((unsigned)f2bf(a[3]) << 16);
    o.z = (unsigned)f2bf(b[0]) | ((unsigned)f2bf(b[1]) << 16);
    o.w = (unsigned)f2bf(b[2]) | ((unsigned)f2bf(b[3]) << 16);
    return o;
}

__device__ __forceinline__ float loadScalar(const void* base, int i, int isbf) {
    return isbf ? bf2f(((const u16*)base)[i]) : ((const float*)base)[i];
}

__device__ __forceinline__ int probe_bf16(const void* p) {
    const int lane = threadIdx.x & 63;
    u16 w = ((const u16*)p)[lane * 2];
    int e = (w >> 7) & 0xff;
    bool sane = (w == 0) || (e >= 100 && e <= 140);
    unsigned long long m = __ballot(sane);
    return __popcll(m) >= 48;
}

// ---------------------------------------------------------------------------
// Fused QKV projection, 128x64 tiles for occupancy (6 blocks/CU grid, 24 KB
// LDS). q,k -> [bh][n][64]; v -> transposed [bh][d][n]. q pre-scaled.
// grid (64, 24): by>>3 selects q/k/v, (by&7)*64 = col tile.
// Fragment-linear LDS (0 conflicts): frag I, lane L at u16 addr I*512 + L*8,
// holding A[m=I*16+(L&15)][k=(L>>4)*8 + j].
// Wave w: rows (w&1)*64 (A-frags wm*4+i), cols (w>>1)*32 (B-frags wn*2+j).
// ---------------------------------------------------------------------------
__global__ __launch_bounds__(256)
void qkv_gemm(const void* __restrict__ X,
              const void* __restrict__ Wq, const void* __restrict__ bq,
              const void* __restrict__ Wk, const void* __restrict__ bk,
              const void* __restrict__ Wv, const void* __restrict__ bv,
              u16* __restrict__ qo, u16* __restrict__ ko, u16* __restrict__ vo,
              int* __restrict__ flags)
{
    __shared__ __align__(16) u16 As[2][128 * 32];   // 8 frags * 512
    __shared__ __align__(16) u16 Bs[2][64 * 32];    // 4 frags * 512

    const int tid  = threadIdx.x;
    const int wave = tid >> 6;
    const int lane = tid & 63;
    const int quad = lane >> 4;
    const int l16  = lane & 15;
    const int wm = wave & 1, wn = wave >> 1;

    const int m0 = blockIdx.x * 128;
    const int by = blockIdx.y;
    const int wsel = by >> 3;
    const int n0 = (by & 7) * 64;

    const void* W  = (wsel == 0) ? Wq : (wsel == 1) ? Wk : Wv;
    const void* bi = (wsel == 0) ? bq : (wsel == 1) ? bk : bv;
    u16* out       = (wsel == 0) ? qo : (wsel == 1) ? ko : vo;
    const float oscale = (wsel == 0) ? 0.04419417382415922f : 1.0f;

    const int fx = probe_bf16(X);
    const int fw = probe_bf16(W);
    const int fb = probe_bf16(bi);
    if (blockIdx.x == 0 && by == 0 && tid == 0) flags[0] = fx;

    f32x4 acc[4][2];
#pragma unroll
    for (int i = 0; i < 4; ++i)
#pragma unroll
        for (int j = 0; j < 2; ++j)
            acc[i][j] = (f32x4){0.f, 0.f, 0.f, 0.f};

    // staging: A frags I = wave, wave+4 (2 chunks); B frag I = wave (1 chunk)
    const int rA1 = m0 + wave * 16 + l16;
    const int rA2 = rA1 + 64;
    const int rB  = n0 + wave * 16 + l16;
    const int cc  = quad * 8;
    const int d1  = wave * 512 + lane * 8;
    const int d2  = d1 + 2048;

    // tile 0 store + tile 1 prefetch
    raw8 a1 = loadraw8(X, (size_t)rA1 * EMB + cc, fx);
    raw8 a2 = loadraw8(X, (size_t)rA2 * EMB + cc, fx);
    raw8 b1 = loadraw8(W, (size_t)rB  * EMB + cc, fw);
    *(uint4*)&As[0][d1] = cvt8(a1, fx);
    *(uint4*)&As[0][d2] = cvt8(a2, fx);
    *(uint4*)&Bs[0][d1] = cvt8(b1, fw);
    a1 = loadraw8(X, (size_t)rA1 * EMB + 32 + cc, fx);
    a2 = loadraw8(X, (size_t)rA2 * EMB + 32 + cc, fx);
    b1 = loadraw8(W, (size_t)rB  * EMB + 32 + cc, fw);
    __syncthreads();

    for (int kt = 0; kt < 16; ++kt) {
        const int buf = kt & 1;
        bf16x8 af[4], bfr[2];
#pragma unroll
        for (int i = 0; i < 4; ++i)
            af[i] = *(const bf16x8*)&As[buf][(wm * 4 + i) * 512 + lane * 8];
#pragma unroll
        for (int j = 0; j < 2; ++j)
            bfr[j] = *(const bf16x8*)&Bs[buf][(wn * 2 + j) * 512 + lane * 8];

        if (kt < 15) {
            const int nb = buf ^ 1;
            *(uint4*)&As[nb][d1] = cvt8(a1, fx);
            *(uint4*)&As[nb][d2] = cvt8(a2, fx);
            *(uint4*)&Bs[nb][d1] = cvt8(b1, fw);
            if (kt < 14) {
                const int kk0 = (kt + 2) * 32;
                a1 = loadraw8(X, (size_t)rA1 * EMB + kk0 + cc, fx);
                a2 = loadraw8(X, (size_t)rA2 * EMB + kk0 + cc, fx);
                b1 = loadraw8(W, (size_t)rB  * EMB + kk0 + cc, fw);
            }
        }

#pragma unroll
        for (int i = 0; i < 4; ++i)
#pragma unroll
            for (int j = 0; j < 2; ++j)
                acc[i][j] = __builtin_amdgcn_mfma_f32_16x16x32_bf16(af[i], bfr[j], acc[i][j], 0, 0, 0);
        __syncthreads();
    }

    // epilogue: q/k -> [bh][n][d]; v -> [bh][d][n]
#pragma unroll
    for (int j = 0; j < 2; ++j) {
        const int col = n0 + wn * 32 + j * 16 + l16;
        const float bv_ = loadScalar(bi, col, fb);
        const int h = col >> 6, d = col & 63;
#pragma unroll
        for (int i = 0; i < 4; ++i) {
#pragma unroll
            for (int r = 0; r < 4; ++r) {
                const int row = m0 + wm * 64 + i * 16 + quad * 4 + r;
                const int b = row >> 12, n = row & 4095;
                const u16 val = f2bf((acc[i][j][r] + bv_) * oscale);
                if (wsel == 2)
                    out[((size_t)((b * HEADS + h) * HD + d)) * NSEQ + n] = val;
                else
                    out[(((size_t)(b * HEADS + h) * NSEQ) + n) * HD + d] = val;
            }
        }
    }
}

// ---------------------------------------------------------------------------
// MFMA flash attention (unchanged from R6). q,k: [bh][n][64]; v: [bh][d][n].
// grid (64, 16).
// ---------------------------------------------------------------------------
#define KP 72
__global__ __launch_bounds__(256)
void attn_mfma(const u16* __restrict__ q, const u16* __restrict__ k,
               const u16* __restrict__ v, u16* __restrict__ ao)
{
    __shared__ __align__(16) u16 Ks[64 * KP];
    __shared__ __align__(16) u16 Vt[64 * KP];
    __shared__ __align__(16) u16 Pb[4][16 * KP];

    const int tid  = threadIdx.x;
    const int wave = tid >> 6;
    const int lane = tid & 63;
    const int quad = lane >> 4;
    const int l16  = lane & 15;

    const int bh = blockIdx.y;
    const int q0 = blockIdx.x * 64;
    const int qw = q0 + wave * 16;
    const size_t base = (size_t)bh * NSEQ * HD;

    bf16x8 qa0 = *(const bf16x8*)(q + base + (size_t)(qw + l16) * HD + quad * 8);
    bf16x8 qa1 = *(const bf16x8*)(q + base + (size_t)(qw + l16) * HD + 32 + quad * 8);

    f32x4 O[4];
    float m_run[4], l_run[4];
#pragma unroll
    for (int t = 0; t < 4; ++t) O[t] = (f32x4){0.f, 0.f, 0.f, 0.f};
#pragma unroll
    for (int r = 0; r < 4; ++r) { m_run[r] = -1e30f; l_run[r] = 0.f; }

    const int row_s[2] = { tid >> 3, (tid + 256) >> 3 };
    const int ch8      = (tid & 7) * 8;

    uint4 pkv[2], pvv[2];
    {
        const int kbase = q0 - 128;
        const int koff  = (kbase < 0) ? 0 : (kbase > NSEQ - 64 ? NSEQ - 64 : kbase);
#pragma unroll
        for (int s = 0; s < 2; ++s) {
            int kg = kbase + row_s[s];
            kg = (kg < 0) ? 0 : (kg > NSEQ - 1 ? NSEQ - 1 : kg);
            pkv[s] = *(const uint4*)(k + base + (size_t)kg * HD + ch8);
            pvv[s] = *(const uint4*)(v + base + (size_t)row_s[s] * NSEQ + koff + ch8);
        }
    }

    for (int c = 0; c < 5; ++c) {
        const int kbase = q0 - 128 + c * 64;

        __syncthreads();
#pragma unroll
        for (int s = 0; s < 2; ++s) {
            *(uint4*)&Ks[row_s[s] * KP + ch8] = pkv[s];
            *(uint4*)&Vt[row_s[s] * KP + ch8] = pvv[s];
        }
        __syncthreads();

        if (c < 4) {
            const int kb2  = kbase + 64;
            const int koff = (kb2 < 0) ? 0 : (kb2 > NSEQ - 64 ? NSEQ - 64 : kb2);
#pragma unroll
            for (int s = 0; s < 2; ++s) {
                int kg = kb2 + row_s[s];
                kg = (kg < 0) ? 0 : (kg > NSEQ - 1 ? NSEQ - 1 : kg);
                pkv[s] = *(const uint4*)(k + base + (size_t)kg * HD + ch8);
                pvv[s] = *(const uint4*)(v + base + (size_t)row_s[s] * NSEQ + koff + ch8);
            }
        }

        f32x4 sv[4];
#pragma unroll
        for (int t = 0; t < 4; ++t) {
            bf16x8 b0 = *(const bf16x8*)&Ks[(t * 16 + l16) * KP + quad * 8];
            bf16x8 b1 = *(const bf16x8*)&Ks[(t * 16 + l16) * KP + 32 + quad * 8];
            f32x4 sacc = (f32x4){0.f, 0.f, 0.f, 0.f};
            sacc = __builtin_amdgcn_mfma_f32_16x16x32_bf16(qa0, b0, sacc, 0, 0, 0);
            sacc = __builtin_amdgcn_mfma_f32_16x16x32_bf16(qa1, b1, sacc, 0, 0, 0);
            sv[t] = sacc;
        }

#pragma unroll
        for (int t = 0; t < 4; ++t) {
            const int jg = kbase + t * 16 + l16;
            const bool jok = ((unsigned)jg) < (unsigned)NSEQ;
#pragma unroll
            for (int r = 0; r < 4; ++r) {
                const int iq = qw + quad * 4 + r;
                const bool band = ((unsigned)(iq - jg + WINDOW)) <= (unsigned)(2 * WINDOW);
                if (!(jok && band)) sv[t][r] = -1e30f;
            }
        }

        float mnew[4];
#pragma unroll
        for (int r = 0; r < 4; ++r)
            mnew[r] = fmaxf(fmaxf(sv[0][r], sv[1][r]), fmaxf(sv[2][r], sv[3][r]));
#pragma unroll
        for (int off = 1; off < 16; off <<= 1)
#pragma unroll
            for (int r = 0; r < 4; ++r)
                mnew[r] = fmaxf(mnew[r], __shfl_xor(mnew[r], off, 64));

        float alpha[4], mi[4];
#pragma unroll
        for (int r = 0; r < 4; ++r) {
            mi[r] = fmaxf(m_run[r], mnew[r]);
            alpha[r] = __expf(m_run[r] - mi[r]);
            m_run[r] = mi[r];
        }

        float p[4][4], lnew[4] = {0.f, 0.f, 0.f, 0.f};
#pragma unroll
        for (int t = 0; t < 4; ++t)
#pragma unroll
            for (int r = 0; r < 4; ++r) {
                float pv = (sv[t][r] > -1e29f) ? __expf(sv[t][r] - mi[r]) : 0.f;
                p[t][r] = pv;
                lnew[r] += pv;
            }
#pragma unroll
        for (int off = 1; off < 16; off <<= 1)
#pragma unroll
            for (int r = 0; r < 4; ++r)
                lnew[r] += __shfl_xor(lnew[r], off, 64);
#pragma unroll
        for (int r = 0; r < 4; ++r)
            l_run[r] = l_run[r] * alpha[r] + lnew[r];

#pragma unroll
        for (int t = 0; t < 4; ++t)
#pragma unroll
            for (int r = 0; r < 4; ++r)
                O[t][r] *= alpha[r];

#pragma unroll
        for (int t = 0; t < 4; ++t)
#pragma unroll
            for (int r = 0; r < 4; ++r)
                Pb[wave][(quad * 4 + r) * KP + t * 16 + l16] = f2bf(p[t][r]);

#pragma unroll
        for (int ks = 0; ks < 2; ++ks) {
            bf16x8 pa = *(const bf16x8*)&Pb[wave][l16 * KP + ks * 32 + quad * 8];
#pragma unroll
            for (int t = 0; t < 4; ++t) {
                bf16x8 vb = *(const bf16x8*)&Vt[(t * 16 + l16) * KP + ks * 32 + quad * 8];
                O[t] = __builtin_amdgcn_mfma_f32_16x16x32_bf16(pa, vb, O[t], 0, 0, 0);
            }
        }
    }

    const int bb = bh >> 3, hh = bh & 7;
    float rl[4];
#pragma unroll
    for (int r = 0; r < 4; ++r) rl[r] = 1.f / l_run[r];
#pragma unroll
    for (int t = 0; t < 4; ++t)
#pragma unroll
        for (int r = 0; r < 4; ++r) {
            const int iq = qw + quad * 4 + r;
            ao[((size_t)(bb * NSEQ + iq)) * EMB + hh * HD + t * 16 + l16] =
                f2bf(O[t][r] * rl[r]);
        }
}

// ---------------------------------------------------------------------------
// Output projection, 64x64 tiles: grid (128, 8) = 1024 blocks (4/CU), 16 KB
// LDS. Wave w: rows (w>>1)*32, cols (w&1)*32; acc 2x2.
// ---------------------------------------------------------------------------
__global__ __launch_bounds__(256)
void out_gemm(const u16* __restrict__ A, const void* __restrict__ W,
              const void* __restrict__ bias, void* __restrict__ out,
              const int* __restrict__ flags)
{
    __shared__ __align__(16) u16 As[2][64 * 32];    // 4 frags * 512
    __shared__ __align__(16) u16 Bs[2][64 * 32];

    const int tid  = threadIdx.x;
    const int wave = tid >> 6;
    const int lane = tid & 63;
    const int quad = lane >> 4;
    const int l16  = lane & 15;
    const int wm = wave >> 1, wn = wave & 1;

    const int m0 = blockIdx.x * 64;
    const int n0 = blockIdx.y * 64;

    const int fw = probe_bf16(W);
    const int fb = probe_bf16(bias);
    const int fo = flags[0];

    f32x4 acc[2][2];
#pragma unroll
    for (int i = 0; i < 2; ++i)
#pragma unroll
        for (int j = 0; j < 2; ++j)
            acc[i][j] = (f32x4){0.f, 0.f, 0.f, 0.f};

    const int rA = m0 + wave * 16 + l16;
    const int rB = n0 + wave * 16 + l16;
    const int cc = quad * 8;
    const int d1 = wave * 512 + lane * 8;

    raw8 a1 = loadraw8(A, (size_t)rA * EMB + cc, 1);
    raw8 b1 = loadraw8(W, (size_t)rB * EMB + cc, fw);
    *(uint4*)&As[0][d1] = a1.lo;
    *(uint4*)&Bs[0][d1] = cvt8(b1, fw);
    a1 = loadraw8(A, (size_t)rA * EMB + 32 + cc, 1);
    b1 = loadraw8(W, (size_t)rB * EMB + 32 + cc, fw);
    __syncthreads();

    for (int kt = 0; kt < 16; ++kt) {
        const int buf = kt & 1;
        bf16x8 af[2], bfr[2];
#pragma unroll
        for (int i = 0; i < 2; ++i)
            af[i] = *(const bf16x8*)&As[buf][(wm * 2 + i) * 512 + lane * 8];
#pragma unroll
        for (int j = 0; j < 2; ++j)
            bfr[j] = *(const bf16x8*)&Bs[buf][(wn * 2 + j) * 512 + lane * 8];

        if (kt < 15) {
            const int nb = buf ^ 1;
            *(uint4*)&As[nb][d1] = a1.lo;
            *(uint4*)&Bs[nb][d1] = cvt8(b1, fw);
            if (kt < 14) {
                const int kk0 = (kt + 2) * 32;
                a1 = loadraw8(A, (size_t)rA * EMB + kk0 + cc, 1);
                b1 = loadraw8(W, (size_t)rB * EMB + kk0 + cc, fw);
            }
        }

#pragma unroll
        for (int i = 0; i < 2; ++i)
#pragma unroll
            for (int j = 0; j < 2; ++j)
                acc[i][j] = __builtin_amdgcn_mfma_f32_16x16x32_bf16(af[i], bfr[j], acc[i][j], 0, 0, 0);
        __syncthreads();
    }

#pragma unroll
    for (int j = 0; j < 2; ++j) {
        const int col = n0 + wn * 32 + j * 16 + l16;
        const float bv_ = loadScalar(bias, col, fb);
#pragma unroll
        for (int i = 0; i < 2; ++i) {
#pragma unroll
            for (int r = 0; r < 4; ++r) {
                const int row = m0 + wm * 32 + i * 16 + quad * 4 + r;
                const float val = acc[i][j][r] + bv_;
                const size_t idx = (size_t)row * EMB + col;
                if (fo) ((u16*)out)[idx] = f2bf(val);
                else    ((float*)out)[idx] = val;
            }
        }
    }
}

extern "C" void kernel_launch(void* const* d_in, const int* in_sizes, int n_in,
                              void* d_out, int out_size, void* d_ws, size_t ws_size,
                              hipStream_t stream)
{
    const size_t HSZ  = (size_t)BATCH * HEADS * NSEQ * HD;   // 4.19M elems
    const size_t HSZB = HSZ * 2;                             // 8.39 MB
    char* base = (char*)d_ws;
    int* flags = (int*)base;
    const size_t off = 256;

    u16 *q, *k, *v, *ao;
    if (ws_size >= off + 4 * HSZB) {
        q  = (u16*)(base + off);
        k  = q + HSZ;
        v  = k + HSZ;
        ao = v + HSZ;
    } else if (ws_size >= off + 3 * HSZB) {
        q  = (u16*)d_out;            // dead before out_gemm writes d_out
        k  = (u16*)(base + off);
        v  = k + HSZ;
        ao = v + HSZ;
    } else {
        q  = (u16*)d_out;
        k  = (u16*)(base + off);
        v  = k + HSZ;
        ao = (u16*)d_in[0];          // x dead after qkv_gemm; restored each launch
    }

    qkv_gemm<<<dim3(64, 24), 256, 0, stream>>>(d_in[0], d_in[1], d_in[2], d_in[3],
                                               d_in[4], d_in[5], d_in[6], q, k, v, flags);
    attn_mfma<<<dim3(64, 16), 256, 0, stream>>>(q, k, v, ao);
    out_gemm<<<dim3(128, 8), 256, 0, stream>>>(ao, d_in[7], d_in[8], d_out, flags);
}

// Round 8
// 151.928 us; speedup vs baseline: 1.4227x; 1.4227x over previous
//
#include <hip/hip_runtime.h>

#define EMB 512
#define HEADS 8
#define HD 64
#define NSEQ 4096
#define BATCH 2
#define WINDOW 128

typedef unsigned short u16;
typedef __attribute__((ext_vector_type(8))) short bf16x8;
typedef __attribute__((ext_vector_type(4))) float f32x4;

#define XS 4194304u   // x elems (2*4096*512)
#define WS 262144u    // one weight matrix elems
#define BS 512u       // one bias elems

__device__ __forceinline__ float bf2f(u16 u) {
    union { unsigned int i; float f; } x;
    x.i = ((unsigned int)u) << 16;
    return x.f;
}

__device__ __forceinline__ u16 f2bf(float f) {
    union { float f; unsigned int i; } x;
    x.f = f;
    unsigned int i = x.i;
    unsigned int lsb = (i >> 16) & 1u;
    i += 0x7fffu + lsb;   // round-to-nearest-even
    return (u16)(i >> 16);
}

struct raw8 { uint4 lo, hi; };

__device__ __forceinline__ raw8 loadraw8(const void* base, size_t off, int isbf) {
    raw8 r;
    if (isbf) {
        r.lo = *(const uint4*)((const u16*)base + off);
    } else {
        const float* f = (const float*)base + off;
        r.lo = *(const uint4*)f;
        r.hi = *(const uint4*)(f + 4);
    }
    return r;
}

__device__ __forceinline__ uint4 cvt8(const raw8& r, int isbf) {
    if (isbf) return r.lo;
    const float* a = (const float*)&r.lo;
    const float* b = (const float*)&r.hi;
    uint4 o;
    o.x = (unsigned)f2bf(a[0]) | ((unsigned)f2bf(a[1]) << 16);
    o.y = (unsigned)f2bf(a[2]) | ((unsigned)f2bf(a[3]) << 16);
    o.z = (unsigned)f2bf(b[0]) | ((unsigned)f2bf(b[1]) << 16);
    o.w = (unsigned)f2bf(b[2]) | ((unsigned)f2bf(b[3]) << 16);
    return o;
}

__device__ __forceinline__ int probe_bf16(const void* p) {
    const int lane = threadIdx.x & 63;
    u16 w = ((const u16*)p)[lane * 2];
    int e = (w >> 7) & 0xff;
    bool sane = (w == 0) || (e >= 100 && e <= 140);
    unsigned long long m = __ballot(sane);
    return __popcll(m) >= 48;
}

// ---------------------------------------------------------------------------
// Pre-pass: convert x, Wq,Wk,Wv,Wo, bq,bk,bv,bo to bf16 in ws (copy if already
// bf16). Halves all downstream GEMM re-read traffic. flags[0] = x dtype (also
// the output dtype). grid: 2561 x 256 covers 5,244,928 elems / 8 per thread.
// ---------------------------------------------------------------------------
__global__ __launch_bounds__(256)
void prepass(const void* __restrict__ x,
             const void* __restrict__ Wq, const void* __restrict__ bq,
             const void* __restrict__ Wk, const void* __restrict__ bk,
             const void* __restrict__ Wv, const void* __restrict__ bv,
             const void* __restrict__ Wo, const void* __restrict__ bo,
             u16* __restrict__ xb, u16* __restrict__ wb, u16* __restrict__ bb,
             int* __restrict__ flags)
{
    const int fx  = probe_bf16(x);
    const int fwq = probe_bf16(Wq), fbq = probe_bf16(bq);
    const int fwk = probe_bf16(Wk), fbk = probe_bf16(bk);
    const int fwv = probe_bf16(Wv), fbv = probe_bf16(bv);
    const int fwo = probe_bf16(Wo), fbo = probe_bf16(bo);
    if (blockIdx.x == 0 && threadIdx.x == 0) flags[0] = fx;

    size_t idx = ((size_t)blockIdx.x * 256 + threadIdx.x) * 8;
    const size_t T_X = XS, T_W = XS + 4 * (size_t)WS, T_ALL = T_W + 4 * (size_t)BS;
    if (idx >= T_ALL) return;

    const void* src; int fl; u16* dst; size_t off;
    if (idx < T_X) {
        src = x; fl = fx; dst = xb; off = idx;
    } else if (idx < T_W) {
        size_t w = idx - T_X;
        int wi = (int)(w / WS); off = w % WS;
        src = (wi == 0) ? Wq : (wi == 1) ? Wk : (wi == 2) ? Wv : Wo;
        fl  = (wi == 0) ? fwq : (wi == 1) ? fwk : (wi == 2) ? fwv : fwo;
        dst = wb + (size_t)wi * WS;
    } else {
        size_t b = idx - T_W;
        int bi = (int)(b / BS); off = b % BS;
        src = (bi == 0) ? bq : (bi == 1) ? bk : (bi == 2) ? bv : bo;
        fl  = (bi == 0) ? fbq : (bi == 1) ? fbk : (bi == 2) ? fbv : fbo;
        dst = bb + (size_t)bi * BS;
    }
    *(uint4*)(dst + off) = cvt8(loadraw8(src, off, fl), fl);
}

// ---------------------------------------------------------------------------
// Fused QKV projection (R4-proven 2-barrier 128x128 core, pure-bf16 inputs).
// q,k,v -> [bh][n][64]; q pre-scaled by 1/sqrt(512). grid (64, 12).
// ---------------------------------------------------------------------------
__global__ __launch_bounds__(256)
void qkv_gemm(const u16* __restrict__ X, const u16* __restrict__ Wall,
              const u16* __restrict__ ball,
              u16* __restrict__ qo, u16* __restrict__ ko, u16* __restrict__ vo)
{
    __shared__ __align__(16) u16 As[128 * 32];
    __shared__ __align__(16) u16 Bs[128 * 32];

    const int tid  = threadIdx.x;
    const int wave = tid >> 6;
    const int lane = tid & 63;
    const int quad = lane >> 4;
    const int l16  = lane & 15;
    const int wm = wave >> 1, wn = wave & 1;

    const int m0 = blockIdx.x * 128;
    const int by = blockIdx.y;
    const int wsel = by >> 2;
    const int n0 = (by & 3) * 128;

    const u16* W  = Wall + (size_t)wsel * WS;
    const u16* bi = ball + (size_t)wsel * BS;
    u16* out      = (wsel == 0) ? qo : (wsel == 1) ? ko : vo;
    const float oscale = (wsel == 0) ? 0.04419417382415922f : 1.0f;

    f32x4 acc[4][4];
#pragma unroll
    for (int i = 0; i < 4; ++i)
#pragma unroll
        for (int j = 0; j < 4; ++j)
            acc[i][j] = (f32x4){0.f, 0.f, 0.f, 0.f};

    const int c1 = tid, c2 = tid + 256;
    const int r1 = c1 >> 2, k1 = (c1 & 3) * 8;
    const int r2 = c2 >> 2, k2 = (c2 & 3) * 8;

    // prefetch tile 0
    uint4 a1 = *(const uint4*)(X + (size_t)(m0 + r1) * EMB + k1);
    uint4 a2 = *(const uint4*)(X + (size_t)(m0 + r2) * EMB + k2);
    uint4 b1 = *(const uint4*)(W + (size_t)(n0 + r1) * EMB + k1);
    uint4 b2 = *(const uint4*)(W + (size_t)(n0 + r2) * EMB + k2);

    for (int kt = 0; kt < 16; ++kt) {
        __syncthreads();
        *(uint4*)&As[c1 * 8] = a1;
        *(uint4*)&As[c2 * 8] = a2;
        *(uint4*)&Bs[c1 * 8] = b1;
        *(uint4*)&Bs[c2 * 8] = b2;
        __syncthreads();

        if (kt < 15) {
            const int kk0 = (kt + 1) * 32;
            a1 = *(const uint4*)(X + (size_t)(m0 + r1) * EMB + kk0 + k1);
            a2 = *(const uint4*)(X + (size_t)(m0 + r2) * EMB + kk0 + k2);
            b1 = *(const uint4*)(W + (size_t)(n0 + r1) * EMB + kk0 + k1);
            b2 = *(const uint4*)(W + (size_t)(n0 + r2) * EMB + kk0 + k2);
        }

        bf16x8 af[4], bfr[4];
#pragma unroll
        for (int i = 0; i < 4; ++i)
            af[i] = *(const bf16x8*)&As[(wm * 64 + i * 16 + l16) * 32 + quad * 8];
#pragma unroll
        for (int j = 0; j < 4; ++j)
            bfr[j] = *(const bf16x8*)&Bs[(wn * 64 + j * 16 + l16) * 32 + quad * 8];
#pragma unroll
        for (int i = 0; i < 4; ++i)
#pragma unroll
            for (int j = 0; j < 4; ++j)
                acc[i][j] = __builtin_amdgcn_mfma_f32_16x16x32_bf16(af[i], bfr[j], acc[i][j], 0, 0, 0);
    }

#pragma unroll
    for (int j = 0; j < 4; ++j) {
        const int col = n0 + wn * 64 + j * 16 + l16;
        const float bv_ = bf2f(bi[col]);
        const int h = col >> 6, d = col & 63;
#pragma unroll
        for (int i = 0; i < 4; ++i) {
#pragma unroll
            for (int r = 0; r < 4; ++r) {
                const int row = m0 + wm * 64 + i * 16 + quad * 4 + r;
                const int b = row >> 12, n = row & 4095;
                out[(((size_t)(b * HEADS + h) * NSEQ) + n) * HD + d] =
                    f2bf((acc[i][j][r] + bv_) * oscale);
            }
        }
    }
}

// ---------------------------------------------------------------------------
// MFMA flash attention (R5 version verbatim). q,k,v: [bh][n][64] bf16.
// grid (64, 16).
// ---------------------------------------------------------------------------
#define KP 72
__global__ __launch_bounds__(256)
void attn_mfma(const u16* __restrict__ q, const u16* __restrict__ k,
               const u16* __restrict__ v, u16* __restrict__ ao)
{
    __shared__ __align__(16) u16 Ks[64 * KP];
    __shared__ __align__(16) u16 Vt[64 * KP];
    __shared__ __align__(16) u16 Pb[4][16 * KP];

    const int tid  = threadIdx.x;
    const int wave = tid >> 6;
    const int lane = tid & 63;
    const int quad = lane >> 4;
    const int l16  = lane & 15;

    const int bh = blockIdx.y;
    const int q0 = blockIdx.x * 64;
    const int qw = q0 + wave * 16;
    const size_t base = (size_t)bh * NSEQ * HD;

    bf16x8 qa0 = *(const bf16x8*)(q + base + (size_t)(qw + l16) * HD + quad * 8);
    bf16x8 qa1 = *(const bf16x8*)(q + base + (size_t)(qw + l16) * HD + 32 + quad * 8);

    f32x4 O[4];
    float m_run[4], l_run[4];
#pragma unroll
    for (int t = 0; t < 4; ++t) O[t] = (f32x4){0.f, 0.f, 0.f, 0.f};
#pragma unroll
    for (int r = 0; r < 4; ++r) { m_run[r] = -1e30f; l_run[r] = 0.f; }

    const int key_s[2] = { tid >> 3, (tid + 256) >> 3 };
    const int ch8      = (tid & 7) * 8;

    uint4 pkv[2], pvv[2];
#pragma unroll
    for (int s = 0; s < 2; ++s) {
        int kg = q0 - 128 + key_s[s];
        kg = (kg < 0) ? 0 : (kg > NSEQ - 1 ? NSEQ - 1 : kg);
        const size_t goff = base + (size_t)kg * HD + ch8;
        pkv[s] = *(const uint4*)(k + goff);
        pvv[s] = *(const uint4*)(v + goff);
    }

    for (int c = 0; c < 5; ++c) {
        const int kbase = q0 - 128 + c * 64;

        __syncthreads();
#pragma unroll
        for (int s = 0; s < 2; ++s) {
            const int key = key_s[s], d0 = ch8;
            *(uint4*)&Ks[key * KP + d0] = pkv[s];
            uint4 vv = pvv[s];
            u16 e[8];
            e[0] = (u16)(vv.x & 0xffff); e[1] = (u16)(vv.x >> 16);
            e[2] = (u16)(vv.y & 0xffff); e[3] = (u16)(vv.y >> 16);
            e[4] = (u16)(vv.z & 0xffff); e[5] = (u16)(vv.z >> 16);
            e[6] = (u16)(vv.w & 0xffff); e[7] = (u16)(vv.w >> 16);
#pragma unroll
            for (int j = 0; j < 8; ++j)
                Vt[(d0 + j) * KP + key] = e[j];
        }
        __syncthreads();

        if (c < 4) {
#pragma unroll
            for (int s = 0; s < 2; ++s) {
                int kg = kbase + 64 + key_s[s];
                kg = (kg < 0) ? 0 : (kg > NSEQ - 1 ? NSEQ - 1 : kg);
                const size_t goff = base + (size_t)kg * HD + ch8;
                pkv[s] = *(const uint4*)(k + goff);
                pvv[s] = *(const uint4*)(v + goff);
            }
        }

        f32x4 sv[4];
#pragma unroll
        for (int t = 0; t < 4; ++t) {
            bf16x8 b0 = *(const bf16x8*)&Ks[(t * 16 + l16) * KP + quad * 8];
            bf16x8 b1 = *(const bf16x8*)&Ks[(t * 16 + l16) * KP + 32 + quad * 8];
            f32x4 sacc = (f32x4){0.f, 0.f, 0.f, 0.f};
            sacc = __builtin_amdgcn_mfma_f32_16x16x32_bf16(qa0, b0, sacc, 0, 0, 0);
            sacc = __builtin_amdgcn_mfma_f32_16x16x32_bf16(qa1, b1, sacc, 0, 0, 0);
            sv[t] = sacc;
        }

#pragma unroll
        for (int t = 0; t < 4; ++t) {
            const int jg = kbase + t * 16 + l16;
            const bool jok = ((unsigned)jg) < (unsigned)NSEQ;
#pragma unroll
            for (int r = 0; r < 4; ++r) {
                const int iq = qw + quad * 4 + r;
                const bool band = ((unsigned)(iq - jg + WINDOW)) <= (unsigned)(2 * WINDOW);
                if (!(jok && band)) sv[t][r] = -1e30f;
            }
        }

        float mnew[4];
#pragma unroll
        for (int r = 0; r < 4; ++r)
            mnew[r] = fmaxf(fmaxf(sv[0][r], sv[1][r]), fmaxf(sv[2][r], sv[3][r]));
#pragma unroll
        for (int off = 1; off < 16; off <<= 1)
#pragma unroll
            for (int r = 0; r < 4; ++r)
                mnew[r] = fmaxf(mnew[r], __shfl_xor(mnew[r], off, 64));

        float alpha[4], mi[4];
#pragma unroll
        for (int r = 0; r < 4; ++r) {
            mi[r] = fmaxf(m_run[r], mnew[r]);
            alpha[r] = __expf(m_run[r] - mi[r]);
            m_run[r] = mi[r];
        }

        float p[4][4], lnew[4] = {0.f, 0.f, 0.f, 0.f};
#pragma unroll
        for (int t = 0; t < 4; ++t)
#pragma unroll
            for (int r = 0; r < 4; ++r) {
                float pv = (sv[t][r] > -1e29f) ? __expf(sv[t][r] - mi[r]) : 0.f;
                p[t][r] = pv;
                lnew[r] += pv;
            }
#pragma unroll
        for (int off = 1; off < 16; off <<= 1)
#pragma unroll
            for (int r = 0; r < 4; ++r)
                lnew[r] += __shfl_xor(lnew[r], off, 64);
#pragma unroll
        for (int r = 0; r < 4; ++r)
            l_run[r] = l_run[r] * alpha[r] + lnew[r];

#pragma unroll
        for (int t = 0; t < 4; ++t)
#pragma unroll
            for (int r = 0; r < 4; ++r)
                O[t][r] *= alpha[r];

#pragma unroll
        for (int t = 0; t < 4; ++t)
#pragma unroll
            for (int r = 0; r < 4; ++r)
                Pb[wave][(quad * 4 + r) * KP + t * 16 + l16] = f2bf(p[t][r]);

#pragma unroll
        for (int ks = 0; ks < 2; ++ks) {
            bf16x8 pa = *(const bf16x8*)&Pb[wave][l16 * KP + ks * 32 + quad * 8];
#pragma unroll
            for (int t = 0; t < 4; ++t) {
                bf16x8 vb = *(const bf16x8*)&Vt[(t * 16 + l16) * KP + ks * 32 + quad * 8];
                O[t] = __builtin_amdgcn_mfma_f32_16x16x32_bf16(pa, vb, O[t], 0, 0, 0);
            }
        }
    }

    const int bb = bh >> 3, hh = bh & 7;
    float rl[4];
#pragma unroll
    for (int r = 0; r < 4; ++r) rl[r] = 1.f / l_run[r];
#pragma unroll
    for (int t = 0; t < 4; ++t)
#pragma unroll
        for (int r = 0; r < 4; ++r) {
            const int iq = qw + quad * 4 + r;
            ao[((size_t)(bb * NSEQ + iq)) * EMB + hh * HD + t * 16 + l16] =
                f2bf(O[t][r] * rl[r]);
        }
}

// ---------------------------------------------------------------------------
// Output projection (R4-proven core, bf16 W/bias). out dtype = flags[0].
// grid (64, 4).
// ---------------------------------------------------------------------------
__global__ __launch_bounds__(256)
void out_gemm(const u16* __restrict__ A, const u16* __restrict__ W,
              const u16* __restrict__ bias, void* __restrict__ out,
              const int* __restrict__ flags)
{
    __shared__ __align__(16) u16 As[128 * 32];
    __shared__ __align__(16) u16 Bs[128 * 32];

    const int tid  = threadIdx.x;
    const int wave = tid >> 6;
    const int lane = tid & 63;
    const int quad = lane >> 4;
    const int l16  = lane & 15;
    const int wm = wave >> 1, wn = wave & 1;

    const int m0 = blockIdx.x * 128;
    const int n0 = blockIdx.y * 128;
    const int fo = flags[0];

    f32x4 acc[4][4];
#pragma unroll
    for (int i = 0; i < 4; ++i)
#pragma unroll
        for (int j = 0; j < 4; ++j)
            acc[i][j] = (f32x4){0.f, 0.f, 0.f, 0.f};

    const int c1 = tid, c2 = tid + 256;
    const int r1 = c1 >> 2, k1 = (c1 & 3) * 8;
    const int r2 = c2 >> 2, k2 = (c2 & 3) * 8;

    uint4 a1 = *(const uint4*)(A + (size_t)(m0 + r1) * EMB + k1);
    uint4 a2 = *(const uint4*)(A + (size_t)(m0 + r2) * EMB + k2);
    uint4 b1 = *(const uint4*)(W + (size_t)(n0 + r1) * EMB + k1);
    uint4 b2 = *(const uint4*)(W + (size_t)(n0 + r2) * EMB + k2);

    for (int kt = 0; kt < 16; ++kt) {
        __syncthreads();
        *(uint4*)&As[c1 * 8] = a1;
        *(uint4*)&As[c2 * 8] = a2;
        *(uint4*)&Bs[c1 * 8] = b1;
        *(uint4*)&Bs[c2 * 8] = b2;
        __syncthreads();

        if (kt < 15) {
            const int kk0 = (kt + 1) * 32;
            a1 = *(const uint4*)(A + (size_t)(m0 + r1) * EMB + kk0 + k1);
            a2 = *(const uint4*)(A + (size_t)(m0 + r2) * EMB + kk0 + k2);
            b1 = *(const uint4*)(W + (size_t)(n0 + r1) * EMB + kk0 + k1);
            b2 = *(const uint4*)(W + (size_t)(n0 + r2) * EMB + kk0 + k2);
        }

        bf16x8 af[4], bfr[4];
#pragma unroll
        for (int i = 0; i < 4; ++i)
            af[i] = *(const bf16x8*)&As[(wm * 64 + i * 16 + l16) * 32 + quad * 8];
#pragma unroll
        for (int j = 0; j < 4; ++j)
            bfr[j] = *(const bf16x8*)&Bs[(wn * 64 + j * 16 + l16) * 32 + quad * 8];
#pragma unroll
        for (int i = 0; i < 4; ++i)
#pragma unroll
            for (int j = 0; j < 4; ++j)
                acc[i][j] = __builtin_amdgcn_mfma_f32_16x16x32_bf16(af[i], bfr[j], acc[i][j], 0, 0, 0);
    }

#pragma unroll
    for (int j = 0; j < 4; ++j) {
        const int col = n0 + wn * 64 + j * 16 + l16;
        const float bv_ = bf2f(bias[col]);
#pragma unroll
        for (int i = 0; i < 4; ++i) {
#pragma unroll
            for (int r = 0; r < 4; ++r) {
                const int row = m0 + wm * 64 + i * 16 + quad * 4 + r;
                const float val = acc[i][j][r] + bv_;
                const size_t idx = (size_t)row * EMB + col;
                if (fo) ((u16*)out)[idx] = f2bf(val);
                else    ((float*)out)[idx] = val;
            }
        }
    }
}

extern "C" void kernel_launch(void* const* d_in, const int* in_sizes, int n_in,
                              void* d_out, int out_size, void* d_ws, size_t ws_size,
                              hipStream_t stream)
{
    const size_t HSZ  = (size_t)BATCH * HEADS * NSEQ * HD;   // 4.19M elems
    char* base = (char*)d_ws;
    int* flags = (int*)base;
    const size_t off = 256;

    u16* xb = (u16*)(base + off);            // 4.19M elems
    u16* wb = xb + XS;                       // 4 * 262144
    u16* bb = wb + 4 * (size_t)WS;           // 4 * 512
    u16* kk = bb + 4 * (size_t)BS;           // k
    u16* vv = kk + HSZ;                      // v
    u16* ao = vv + HSZ;                      // ao
    u16* qq = ao + HSZ;                      // q (tier-1)

    const size_t need_t1 = off + 2 * (XS + 4 * (size_t)WS + 4 * (size_t)BS + 4 * HSZ);
    if (ws_size < need_t1) {
        qq = (u16*)d_out;                    // q dead before out_gemm writes d_out
    }

    prepass<<<dim3(2561), 256, 0, stream>>>(d_in[0], d_in[1], d_in[2], d_in[3],
                                            d_in[4], d_in[5], d_in[6], d_in[7],
                                            d_in[8], xb, wb, bb, flags);
    qkv_gemm<<<dim3(64, 12), 256, 0, stream>>>(xb, wb, bb, qq, kk, vv);
    attn_mfma<<<dim3(64, 16), 256, 0, stream>>>(qq, kk, vv, ao);
    out_gemm<<<dim3(64, 4), 256, 0, stream>>>(ao, wb + 3 * (size_t)WS, bb + 3 * (size_t)BS,
                                              d_out, flags);
}